// Round 4
// baseline (5372.272 us; speedup 1.0000x reference)
//
#include <hip/hip_runtime.h>
#include <math.h>

// MACE layer, f32. Round 10: R9 de-spilled (WRITE 4.26GB->81MB, VGPR 68) but
// k_edge still latency-bound: VALU 21%, HBM 2.6%, Occ 35%/50%cap. Stalls =
// (a) w4 GEMM loops issue dependent L2 loads with zero pipelining regs,
// (b) serial es/ev gathers, (c) LDS 36KB caps 4 blocks/CU. Fix: window 8->6
// nodes (LDS 32.2KB -> 5 blocks/CU, launch_bounds(256,5)); explicit one-step
// register double-buffer of w4/w2/w3 in every GEMM loop; es/ev gathers
// preloaded one edge ahead (hide under TP+atomics); es-group split 2x4 edges
// to keep peak live regs ~90 < 102 cap (no spill).
// K1: node pre   Ksort: hist/scan/permute   K2: fused edge   K3: epilogue

#define N_NODES 32768
#define N_EDGES 524288
#define FCH 128
#define NBASIS 8
#define HDIM 64
#define CE 64      // edges per block in K2 (N_EDGES = 8192 * CE exactly)
#define NWIN 6     // receiver-node LDS window
#define NT1 8      // nodes per block in K1/K3
#define MIXW 640   // NP * FCH (w4 row stride)

__device__ __forceinline__ float silu(float x) { return x / (1.0f + __expf(-x)); }

constexpr float INV_SQRT128  = 0.08838834764831845f;
constexpr float INV_SQRT8    = 0.35355339059327373f;
constexpr float INV_64       = 0.125f;                 // 1/sqrt(64)
constexpr float INV_SQRT10   = 0.31622776601683794f;
constexpr float INV_SQRT1280 = 0.027950849718747374f;  // 1/sqrt(F*Z)
constexpr float INV_SQRT16   = 0.25f;
constexpr float EPSN         = 0.125f;
constexpr float C_P1         = 0.07216878364870323f;   // 1/sqrt(3) * 1/64... (INV_SQRT3*INV_64)
constexpr float C_P4         = 0.08838834764831845f;   // INV_SQRT2 * INV_64

// ---------------------------------------------------------------- K1: node pre
__global__ __launch_bounds__(128) void k_node_pre(
    const float* __restrict__ ns, const float* __restrict__ nv,
    const float* __restrict__ w_skip, const float* __restrict__ w_up0,
    const float* __restrict__ w_up1, const int* __restrict__ species,
    float* __restrict__ hs, float* __restrict__ hv0, float* __restrict__ hv1,
    float* __restrict__ hv2, float* __restrict__ self_conn)
{
    __shared__ float ls[NT1][FCH];
    __shared__ float lv[3][NT1][FCH];
    __shared__ int lsp[NT1];
    const int g  = threadIdx.x;
    const int n0 = blockIdx.x * NT1;

    #pragma unroll
    for (int n = 0; n < NT1; ++n)
        ls[n][g] = ns[(size_t)(n0 + n) * FCH + g];
    for (int idx = g; idx < NT1 * FCH; idx += 128) {
        int n = idx >> 7, f = idx & 127;
        const float* src = nv + ((size_t)(n0 + n) * FCH + f) * 3;
        lv[0][n][f] = src[0];
        lv[1][n][f] = src[1];
        lv[2][n][f] = src[2];
    }
    if (g < NT1) lsp[g] = species[n0 + g];
    __syncthreads();

    const float* wk[NT1];
    #pragma unroll
    for (int n = 0; n < NT1; ++n)
        wk[n] = w_skip + (size_t)lsp[n] * FCH * FCH + g;

    float a_s[NT1], a0[NT1], a1[NT1], a2[NT1], a_k[NT1];
    #pragma unroll
    for (int n = 0; n < NT1; ++n) { a_s[n]=0; a0[n]=0; a1[n]=0; a2[n]=0; a_k[n]=0; }

    #pragma unroll 2
    for (int f = 0; f < FCH; ++f) {
        float u0 = w_up0[f * FCH + g];
        float u1 = w_up1[f * FCH + g];
        #pragma unroll
        for (int n = 0; n < NT1; ++n) {
            float s = ls[n][f];
            a_s[n] += s * u0;
            a0[n]  += lv[0][n][f] * u1;
            a1[n]  += lv[1][n][f] * u1;
            a2[n]  += lv[2][n][f] * u1;
            a_k[n] += s * wk[n][(size_t)f * FCH];
        }
    }
    #pragma unroll
    for (int n = 0; n < NT1; ++n) {
        size_t o = (size_t)(n0 + n) * FCH + g;
        hs[o]  = a_s[n] * INV_SQRT128;
        hv0[o] = a0[n]  * INV_SQRT128;
        hv1[o] = a1[n]  * INV_SQRT128;
        hv2[o] = a2[n]  * INV_SQRT128;
        self_conn[o] = a_k[n] * INV_SQRT1280;
    }
}

// ---------------------------------------------------------------- sort kernels
__global__ __launch_bounds__(256) void k_hist(
    const int* __restrict__ recv, int* __restrict__ counts)
{
    int e = blockIdx.x * 256 + threadIdx.x;
    atomicAdd(&counts[recv[e]], 1);
}

__global__ __launch_bounds__(1024) void k_scan(
    const int* __restrict__ counts, int* __restrict__ cursor)
{
    __shared__ int part[1024];
    const int t  = threadIdx.x;
    const int b0 = t * 32;
    int local[32];
    int s = 0;
    #pragma unroll
    for (int i = 0; i < 32; ++i) { local[i] = s; s += counts[b0 + i]; }
    part[t] = s;
    __syncthreads();
    for (int off = 1; off < 1024; off <<= 1) {
        int v   = part[t];
        int add = (t >= off) ? part[t - off] : 0;
        __syncthreads();
        part[t] = v + add;
        __syncthreads();
    }
    int base = (t == 0) ? 0 : part[t - 1];
    #pragma unroll
    for (int i = 0; i < 32; ++i) cursor[b0 + i] = base + local[i];
}

__global__ __launch_bounds__(256) void k_permute(
    const int* __restrict__ recv, int* __restrict__ cursor,
    int* __restrict__ perm)
{
    int e = blockIdx.x * 256 + threadIdx.x;
    int pos = atomicAdd(&cursor[recv[e]], 1);
    perm[pos] = e;
}

// ---------------------------------------------------------------- K2: fused
// Block = 64 receiver-sorted edges. MLP wave-private in hA. All GEMM loops
// register-double-buffer their weight loads; sender gathers preloaded one
// edge ahead. 6-node LDS window, overflow + flush via global atomics.
__global__ __launch_bounds__(256, 5) void k_edge(
    const float* __restrict__ vectors, const float* __restrict__ radial,
    const float* __restrict__ w1, const float* __restrict__ w2,
    const float* __restrict__ w3, const float* __restrict__ w4,
    const float* __restrict__ hs, const float* __restrict__ hv0,
    const float* __restrict__ hv1, const float* __restrict__ hv2,
    const int* __restrict__ senders, const int* __restrict__ receivers,
    const int* __restrict__ perm,
    float* __restrict__ agg_s, float* __restrict__ agg_v0,
    float* __restrict__ agg_v1, float* __restrict__ agg_v2)
{
    __shared__ __align__(16) float lrad[CE * NBASIS];   // 2KB
    __shared__ __align__(16) float hA[CE * HDIM];       // 16KB
    __shared__ float lY[CE][3];
    __shared__ int leid[CE], lsend[CE], lrecv[CE];
    __shared__ __align__(16) float laccS[NWIN * FCH];   // 3KB each
    __shared__ __align__(16) float laccV0[NWIN * FCH];
    __shared__ __align__(16) float laccV1[NWIN * FCH];
    __shared__ __align__(16) float laccV2[NWIN * FCH];

    const int tid = threadIdx.x;
    const int p0  = blockIdx.x * CE;

    if (tid < CE) {
        int eid = perm[p0 + tid];
        leid[tid]  = eid;
        lsend[tid] = senders[eid];
        lrecv[tid] = receivers[eid];
        float vx = vectors[(size_t)eid * 3 + 0];
        float vy = vectors[(size_t)eid * 3 + 1];
        float vz = vectors[(size_t)eid * 3 + 2];
        float rn = 1.0f / (sqrtf(vx*vx + vy*vy + vz*vz) + 1e-9f);
        lY[tid][0] = vx * rn; lY[tid][1] = vy * rn; lY[tid][2] = vz * rn;
    }
    for (int i = tid; i < NWIN * FCH; i += 256) {
        laccS[i] = 0.f; laccV0[i] = 0.f; laccV1[i] = 0.f; laccV2[i] = 0.f;
    }
    __syncthreads();
    for (int idx = tid; idx < CE * NBASIS; idx += 256)
        lrad[idx] = radial[(size_t)leid[idx >> 3] * NBASIS + (idx & 7)];
    __syncthreads();   // barrier #2 (last before flush)

    // ---- radial MLP, wave-private rows [grp*16, +16) ----
    const int k    = tid & 63;
    const int grp  = tid >> 6;
    const int e_lo = grp * 16;

    {   // layer 1 (8->64), direct per-row
        float w1c[NBASIS];
        #pragma unroll
        for (int j = 0; j < NBASIS; ++j) w1c[j] = w1[j * HDIM + k];
        #pragma unroll 4
        for (int e = 0; e < 16; ++e) {
            const float* r = &lrad[(e_lo + e) * NBASIS];
            float a = r[0]*w1c[0] + r[1]*w1c[1] + r[2]*w1c[2] + r[3]*w1c[3]
                    + r[4]*w1c[4] + r[5]*w1c[5] + r[6]*w1c[6] + r[7]*w1c[7];
            hA[(e_lo + e) * HDIM + k] = silu(a * INV_SQRT8);
        }
    }
    {   // layer 2 (64->64): j-outer, acc[16], one-step weight prefetch
        float acc[16];
        #pragma unroll
        for (int e = 0; e < 16; ++e) acc[e] = 0.f;
        float na = w2[0 * HDIM + k], nb = w2[1 * HDIM + k];
        float ncv = w2[2 * HDIM + k], nd = w2[3 * HDIM + k];
        #pragma unroll 2
        for (int j = 0; j < HDIM - 4; j += 4) {
            float wa = na, wb = nb, wc = ncv, wd = nd;
            na  = w2[(j+4) * HDIM + k];
            nb  = w2[(j+5) * HDIM + k];
            ncv = w2[(j+6) * HDIM + k];
            nd  = w2[(j+7) * HDIM + k];
            #pragma unroll
            for (int e = 0; e < 16; ++e) {
                float4 h = *(float4*)&hA[(e_lo + e) * HDIM + j];
                acc[e] += h.x*wa + h.y*wb + h.z*wc + h.w*wd;
            }
        }
        #pragma unroll
        for (int e = 0; e < 16; ++e) {
            float4 h = *(float4*)&hA[(e_lo + e) * HDIM + 60];
            acc[e] += h.x*na + h.y*nb + h.z*ncv + h.w*nd;
        }
        #pragma unroll
        for (int e = 0; e < 16; ++e)
            hA[(e_lo + e) * HDIM + k] = silu(acc[e] * INV_64);
    }
    {   // layer 3 (64->64), same shape
        float acc[16];
        #pragma unroll
        for (int e = 0; e < 16; ++e) acc[e] = 0.f;
        float na = w3[0 * HDIM + k], nb = w3[1 * HDIM + k];
        float ncv = w3[2 * HDIM + k], nd = w3[3 * HDIM + k];
        #pragma unroll 2
        for (int j = 0; j < HDIM - 4; j += 4) {
            float wa = na, wb = nb, wc = ncv, wd = nd;
            na  = w3[(j+4) * HDIM + k];
            nb  = w3[(j+5) * HDIM + k];
            ncv = w3[(j+6) * HDIM + k];
            nd  = w3[(j+7) * HDIM + k];
            #pragma unroll
            for (int e = 0; e < 16; ++e) {
                float4 h = *(float4*)&hA[(e_lo + e) * HDIM + j];
                acc[e] += h.x*wa + h.y*wb + h.z*wc + h.w*wd;
            }
        }
        #pragma unroll
        for (int e = 0; e < 16; ++e) {
            float4 h = *(float4*)&hA[(e_lo + e) * HDIM + 60];
            acc[e] += h.x*na + h.y*nb + h.z*ncv + h.w*nd;
        }
        #pragma unroll
        for (int e = 0; e < 16; ++e)
            hA[(e_lo + e) * HDIM + k] = silu(acc[e] * INV_64);
    }

    // ---- operand-grouped path GEMMs + TP ----
    const int fq = (tid & 31) * 4;
    const int eg = tid >> 5;
    const int eb = eg * 8;
    const int r0 = lrecv[0];
    const float* w4q = w4 + fq;

    // ===== es-group: paths 0,2 in two 4-edge subgroups =====
    #pragma unroll
    for (int sub = 0; sub < 2; ++sub) {
        const int e0 = eb + sub * 4;
        float ma[4][4], mc[4][4];
        #pragma unroll
        for (int q = 0; q < 4; ++q)
            #pragma unroll
            for (int c = 0; c < 4; ++c) { ma[q][c] = 0.f; mc[q][c] = 0.f; }

        float4 n0a = *(const float4*)(w4q + 0 * MIXW);
        float4 n0b = *(const float4*)(w4q + 1 * MIXW);
        float4 n2a = *(const float4*)(w4q + 0 * MIXW + 2*FCH);
        float4 n2b = *(const float4*)(w4q + 1 * MIXW + 2*FCH);
        #pragma unroll 4
        for (int j = 0; j < HDIM - 2; j += 2) {
            float4 w0a = n0a, w0b = n0b, w2a = n2a, w2b = n2b;
            n0a = *(const float4*)(w4q + (size_t)(j+2) * MIXW);
            n0b = *(const float4*)(w4q + (size_t)(j+3) * MIXW);
            n2a = *(const float4*)(w4q + (size_t)(j+2) * MIXW + 2*FCH);
            n2b = *(const float4*)(w4q + (size_t)(j+3) * MIXW + 2*FCH);
            #pragma unroll
            for (int q = 0; q < 4; ++q) {
                float2 h = *(float2*)&hA[(e0 + q) * HDIM + j];
                ma[q][0] += h.x*w0a.x + h.y*w0b.x;
                ma[q][1] += h.x*w0a.y + h.y*w0b.y;
                ma[q][2] += h.x*w0a.z + h.y*w0b.z;
                ma[q][3] += h.x*w0a.w + h.y*w0b.w;
                mc[q][0] += h.x*w2a.x + h.y*w2b.x;
                mc[q][1] += h.x*w2a.y + h.y*w2b.y;
                mc[q][2] += h.x*w2a.z + h.y*w2b.z;
                mc[q][3] += h.x*w2a.w + h.y*w2b.w;
            }
        }
        #pragma unroll
        for (int q = 0; q < 4; ++q) {   // j = 62 epilogue
            float2 h = *(float2*)&hA[(e0 + q) * HDIM + 62];
            ma[q][0] += h.x*n0a.x + h.y*n0b.x;
            ma[q][1] += h.x*n0a.y + h.y*n0b.y;
            ma[q][2] += h.x*n0a.z + h.y*n0b.z;
            ma[q][3] += h.x*n0a.w + h.y*n0b.w;
            mc[q][0] += h.x*n2a.x + h.y*n2b.x;
            mc[q][1] += h.x*n2a.y + h.y*n2b.y;
            mc[q][2] += h.x*n2a.z + h.y*n2b.z;
            mc[q][3] += h.x*n2a.w + h.y*n2b.w;
        }

        float4 esv = *(const float4*)(hs + (size_t)lsend[e0] * FCH + fq);
        #pragma unroll
        for (int q = 0; q < 4; ++q) {
            float4 esn;
            if (q < 3) esn = *(const float4*)(hs + (size_t)lsend[e0+q+1] * FCH + fq);
            const int e  = e0 + q;
            const int nl = lrecv[e] - r0;
            float es0 = esv.x, es1 = esv.y, es2 = esv.z, es3 = esv.w;
            const float Yx = lY[e][0], Yy = lY[e][1], Yz = lY[e][2];
            float s0 = ma[q][0]*es0*INV_64, s1 = ma[q][1]*es1*INV_64;
            float s2 = ma[q][2]*es2*INV_64, s3 = ma[q][3]*es3*INV_64;
            float t0 = mc[q][0]*es0*INV_64, t1 = mc[q][1]*es1*INV_64;
            float t2 = mc[q][2]*es2*INV_64, t3 = mc[q][3]*es3*INV_64;
            if (nl < NWIN) {
                const int b = nl * FCH + fq;
                atomicAdd(&laccS[b+0], s0); atomicAdd(&laccS[b+1], s1);
                atomicAdd(&laccS[b+2], s2); atomicAdd(&laccS[b+3], s3);
                atomicAdd(&laccV0[b+0], t0*Yx); atomicAdd(&laccV0[b+1], t1*Yx);
                atomicAdd(&laccV0[b+2], t2*Yx); atomicAdd(&laccV0[b+3], t3*Yx);
                atomicAdd(&laccV1[b+0], t0*Yy); atomicAdd(&laccV1[b+1], t1*Yy);
                atomicAdd(&laccV1[b+2], t2*Yy); atomicAdd(&laccV1[b+3], t3*Yy);
                atomicAdd(&laccV2[b+0], t0*Yz); atomicAdd(&laccV2[b+1], t1*Yz);
                atomicAdd(&laccV2[b+2], t2*Yz); atomicAdd(&laccV2[b+3], t3*Yz);
            } else {
                const size_t go = (size_t)lrecv[e] * FCH + fq;
                atomicAdd(&agg_s[go+0], s0); atomicAdd(&agg_s[go+1], s1);
                atomicAdd(&agg_s[go+2], s2); atomicAdd(&agg_s[go+3], s3);
                atomicAdd(&agg_v0[go+0], t0*Yx); atomicAdd(&agg_v0[go+1], t1*Yx);
                atomicAdd(&agg_v0[go+2], t2*Yx); atomicAdd(&agg_v0[go+3], t3*Yx);
                atomicAdd(&agg_v1[go+0], t0*Yy); atomicAdd(&agg_v1[go+1], t1*Yy);
                atomicAdd(&agg_v1[go+2], t2*Yy); atomicAdd(&agg_v1[go+3], t3*Yy);
                atomicAdd(&agg_v2[go+0], t0*Yz); atomicAdd(&agg_v2[go+1], t1*Yz);
                atomicAdd(&agg_v2[go+2], t2*Yz); atomicAdd(&agg_v2[go+3], t3*Yz);
            }
            esv = esn;
        }
    }

    // ===== ev-group: paths 1,3,4 in two 4-edge halves =====
    #pragma unroll
    for (int half = 0; half < 2; ++half) {
        const int e0 = eb + half * 4;
        float m1[4][4], m3[4][4], m5[4][4];
        #pragma unroll
        for (int q = 0; q < 4; ++q)
            #pragma unroll
            for (int c = 0; c < 4; ++c) { m1[q][c]=0.f; m3[q][c]=0.f; m5[q][c]=0.f; }

        float4 n1 = *(const float4*)(w4q + 0 * MIXW + 1*FCH);
        float4 n3 = *(const float4*)(w4q + 0 * MIXW + 3*FCH);
        float4 n4 = *(const float4*)(w4q + 0 * MIXW + 4*FCH);
        #pragma unroll 4
        for (int j = 0; j < HDIM - 1; ++j) {
            float4 wa1 = n1, wa3 = n3, wa4 = n4;
            n1 = *(const float4*)(w4q + (size_t)(j+1) * MIXW + 1*FCH);
            n3 = *(const float4*)(w4q + (size_t)(j+1) * MIXW + 3*FCH);
            n4 = *(const float4*)(w4q + (size_t)(j+1) * MIXW + 4*FCH);
            #pragma unroll
            for (int q = 0; q < 4; ++q) {
                float h = hA[(e0 + q) * HDIM + j];
                m1[q][0] += h*wa1.x; m1[q][1] += h*wa1.y;
                m1[q][2] += h*wa1.z; m1[q][3] += h*wa1.w;
                m3[q][0] += h*wa3.x; m3[q][1] += h*wa3.y;
                m3[q][2] += h*wa3.z; m3[q][3] += h*wa3.w;
                m5[q][0] += h*wa4.x; m5[q][1] += h*wa4.y;
                m5[q][2] += h*wa4.z; m5[q][3] += h*wa4.w;
            }
        }
        #pragma unroll
        for (int q = 0; q < 4; ++q) {   // j = 63 epilogue
            float h = hA[(e0 + q) * HDIM + 63];
            m1[q][0] += h*n1.x; m1[q][1] += h*n1.y;
            m1[q][2] += h*n1.z; m1[q][3] += h*n1.w;
            m3[q][0] += h*n3.x; m3[q][1] += h*n3.y;
            m3[q][2] += h*n3.z; m3[q][3] += h*n3.w;
            m5[q][0] += h*n4.x; m5[q][1] += h*n4.y;
            m5[q][2] += h*n4.z; m5[q][3] += h*n4.w;
        }

        size_t so = (size_t)lsend[e0] * FCH + fq;
        float4 a0 = *(const float4*)(hv0 + so);
        float4 a1 = *(const float4*)(hv1 + so);
        float4 a2 = *(const float4*)(hv2 + so);
        #pragma unroll
        for (int q = 0; q < 4; ++q) {
            float4 b0, b1, b2;
            if (q < 3) {
                size_t sn = (size_t)lsend[e0+q+1] * FCH + fq;
                b0 = *(const float4*)(hv0 + sn);
                b1 = *(const float4*)(hv1 + sn);
                b2 = *(const float4*)(hv2 + sn);
            }
            const int e  = e0 + q;
            const int nl = lrecv[e] - r0;
            const float Yx = lY[e][0], Yy = lY[e][1], Yz = lY[e][2];
            float ev0[4] = { a0.x, a0.y, a0.z, a0.w };
            float ev1[4] = { a1.x, a1.y, a1.z, a1.w };
            float ev2[4] = { a2.x, a2.y, a2.z, a2.w };
            if (nl < NWIN) {
                const int b = nl * FCH + fq;
                #pragma unroll
                for (int c = 0; c < 4; ++c) {
                    float d   = ev0[c]*Yx + ev1[c]*Yy + ev2[c]*Yz;
                    float sv  = m1[q][c] * d * C_P1;
                    float m3v = m3[q][c] * INV_64;
                    float m4v = m5[q][c] * C_P4;
                    float v0 = m3v*ev0[c] + m4v*(ev1[c]*Yz - ev2[c]*Yy);
                    float v1 = m3v*ev1[c] + m4v*(ev2[c]*Yx - ev0[c]*Yz);
                    float v2 = m3v*ev2[c] + m4v*(ev0[c]*Yy - ev1[c]*Yx);
                    atomicAdd(&laccS[b + c],  sv);
                    atomicAdd(&laccV0[b + c], v0);
                    atomicAdd(&laccV1[b + c], v1);
                    atomicAdd(&laccV2[b + c], v2);
                }
            } else {
                const size_t go = (size_t)lrecv[e] * FCH + fq;
                #pragma unroll
                for (int c = 0; c < 4; ++c) {
                    float d   = ev0[c]*Yx + ev1[c]*Yy + ev2[c]*Yz;
                    float sv  = m1[q][c] * d * C_P1;
                    float m3v = m3[q][c] * INV_64;
                    float m4v = m5[q][c] * C_P4;
                    float v0 = m3v*ev0[c] + m4v*(ev1[c]*Yz - ev2[c]*Yy);
                    float v1 = m3v*ev1[c] + m4v*(ev2[c]*Yx - ev0[c]*Yz);
                    float v2 = m3v*ev2[c] + m4v*(ev0[c]*Yy - ev1[c]*Yx);
                    atomicAdd(&agg_s[go + c],  sv);
                    atomicAdd(&agg_v0[go + c], v0);
                    atomicAdd(&agg_v1[go + c], v1);
                    atomicAdd(&agg_v2[go + c], v2);
                }
            }
            a0 = b0; a1 = b1; a2 = b2;
        }
    }

    __syncthreads();   // barrier #3: window complete
    int span = lrecv[CE - 1] - r0;
    if (span > NWIN - 1) span = NWIN - 1;
    const int tot = (span + 1) * FCH;
    for (int i = tid; i < tot; i += 256) {
        const size_t go = (size_t)(r0 + (i >> 7)) * FCH + (i & 127);
        atomicAdd(&agg_s[go],  laccS[i]);
        atomicAdd(&agg_v0[go], laccV0[i]);
        atomicAdd(&agg_v1[go], laccV1[i]);
        atomicAdd(&agg_v2[go], laccV2[i]);
    }
}

// ---------------------------------------------------------------- K3: epilogue
__global__ __launch_bounds__(128) void k_epilogue(
    const float* __restrict__ agg_s, const float* __restrict__ agg_v0,
    const float* __restrict__ agg_v1, const float* __restrict__ agg_v2,
    const float* __restrict__ self_conn, const int* __restrict__ species,
    const float* __restrict__ w_down0, const float* __restrict__ w_down1,
    const float* __restrict__ w_sc, const float* __restrict__ w_post,
    const float* __restrict__ w_read1, const float* __restrict__ w_read2,
    float* __restrict__ out0, float* __restrict__ feats_out)
{
    __shared__ float lS[NT1][FCH];
    __shared__ float lV[3][NT1][FCH];
    __shared__ float fA[NT1][FCH];
    __shared__ float fB[NT1][FCH];
    __shared__ int lsp[NT1];
    const int g  = threadIdx.x;
    const int n0 = blockIdx.x * NT1;

    #pragma unroll
    for (int n = 0; n < NT1; ++n) {
        size_t o = (size_t)(n0 + n) * FCH + g;
        lS[n][g]    = agg_s[o]  * EPSN;
        lV[0][n][g] = agg_v0[o] * EPSN;
        lV[1][n][g] = agg_v1[o] * EPSN;
        lV[2][n][g] = agg_v2[o] * EPSN;
    }
    if (g < NT1) lsp[g] = species[n0 + g];
    __syncthreads();

    float xs[NT1], xv0[NT1], xv1[NT1], xv2[NT1];
    #pragma unroll
    for (int n = 0; n < NT1; ++n) { xs[n]=0; xv0[n]=0; xv1[n]=0; xv2[n]=0; }
    #pragma unroll 2
    for (int f = 0; f < FCH; ++f) {
        float d0 = w_down0[f * FCH + g];
        float d1 = w_down1[f * FCH + g];
        #pragma unroll
        for (int n = 0; n < NT1; ++n) {
            xs[n]  += lS[n][f] * d0;
            xv0[n] += lV[0][n][f] * d1;
            xv1[n] += lV[1][n][f] * d1;
            xv2[n] += lV[2][n][f] * d1;
        }
    }
    #pragma unroll
    for (int n = 0; n < NT1; ++n) {
        float s  = xs[n]  * INV_SQRT128;
        float v0 = xv0[n] * INV_SQRT128;
        float v1 = xv1[n] * INV_SQRT128;
        float v2 = xv2[n] * INV_SQRT128;
        int z = lsp[n];
        float wz0 = w_sc[((size_t)z * 3 + 0) * FCH + g] * INV_SQRT10;
        float wz1 = w_sc[((size_t)z * 3 + 1) * FCH + g] * INV_SQRT10;
        float wz2 = w_sc[((size_t)z * 3 + 2) * FCH + g] * INV_SQRT10;
        fA[n][g] = wz0 * s + wz1 * s * s + wz2 * (v0*v0 + v1*v1 + v2*v2);
    }
    __syncthreads();

    float fc[NT1];
    #pragma unroll
    for (int n = 0; n < NT1; ++n) fc[n] = 0;
    #pragma unroll 2
    for (int f = 0; f < FCH; ++f) {
        float wp = w_post[f * FCH + g];
        #pragma unroll
        for (int n = 0; n < NT1; ++n) fc[n] += fA[n][f] * wp;
    }
    #pragma unroll
    for (int n = 0; n < NT1; ++n) {
        size_t o = (size_t)(n0 + n) * FCH + g;
        float v = fc[n] * INV_SQRT128 + self_conn[o];
        fB[n][g] = v;
        feats_out[o] = v;
    }
    __syncthreads();

    const int n2 = g >> 4, r = g & 15;
    float acc = 0.f;
    for (int f = 0; f < FCH; ++f) acc += fB[n2][f] * w_read1[f * 16 + r];
    float t = silu(acc * INV_SQRT128);
    float val = t * w_read2[r];
    val += __shfl_down(val, 8, 16);
    val += __shfl_down(val, 4, 16);
    val += __shfl_down(val, 2, 16);
    val += __shfl_down(val, 1, 16);
    if (r == 0) out0[n0 + n2] = val * INV_SQRT16;
}

// ---------------------------------------------------------------- launch
extern "C" void kernel_launch(void* const* d_in, const int* in_sizes, int n_in,
                              void* d_out, int out_size, void* d_ws, size_t ws_size,
                              hipStream_t stream) {
    (void)in_sizes; (void)n_in; (void)out_size; (void)ws_size;
    const float* vectors      = (const float*)d_in[0];
    const float* node_scalars = (const float*)d_in[1];
    const float* node_vectors = (const float*)d_in[2];
    const float* radial       = (const float*)d_in[3];
    const float* w_skip       = (const float*)d_in[4];
    const float* w_up0        = (const float*)d_in[5];
    const float* w_up1        = (const float*)d_in[6];
    const float* mlp_w1       = (const float*)d_in[7];
    const float* mlp_w2       = (const float*)d_in[8];
    const float* mlp_w3       = (const float*)d_in[9];
    const float* mlp_w4       = (const float*)d_in[10];
    const float* w_down0      = (const float*)d_in[11];
    const float* w_down1      = (const float*)d_in[12];
    const float* w_sc         = (const float*)d_in[13];
    const float* w_post       = (const float*)d_in[14];
    const float* w_read1      = (const float*)d_in[15];
    const float* w_read2      = (const float*)d_in[16];
    const int*   senders      = (const int*)d_in[17];
    const int*   receivers    = (const int*)d_in[18];
    const int*   species      = (const int*)d_in[19];

    const size_t NF = (size_t)N_NODES * FCH;
    float* ws     = (float*)d_ws;
    float* hs     = ws;
    float* hv0    = ws + 1 * NF;
    float* hv1    = ws + 2 * NF;
    float* hv2    = ws + 3 * NF;
    float* agg_s  = ws + 4 * NF;
    float* agg_v0 = ws + 5 * NF;
    float* agg_v1 = ws + 6 * NF;
    float* agg_v2 = ws + 7 * NF;
    int* counts   = (int*)(ws + 8 * NF);      // [N]
    int* cursor   = counts + N_NODES;         // [N]
    int* perm     = cursor + N_NODES;         // [E]

    float* out       = (float*)d_out;
    float* feats     = out + N_NODES;   // final feats output
    float* self_conn = feats;           // scratch until epilogue overwrites

    hipMemsetAsync(counts, 0, N_NODES * sizeof(int), stream);
    hipMemsetAsync(agg_s, 0, 4 * NF * sizeof(float), stream);

    k_node_pre<<<N_NODES / NT1, 128, 0, stream>>>(
        node_scalars, node_vectors, w_skip, w_up0, w_up1, species,
        hs, hv0, hv1, hv2, self_conn);

    k_hist<<<N_EDGES / 256, 256, 0, stream>>>(receivers, counts);
    k_scan<<<1, 1024, 0, stream>>>(counts, cursor);
    k_permute<<<N_EDGES / 256, 256, 0, stream>>>(receivers, cursor, perm);

    k_edge<<<N_EDGES / CE, 256, 0, stream>>>(
        vectors, radial, mlp_w1, mlp_w2, mlp_w3, mlp_w4,
        hs, hv0, hv1, hv2, senders, receivers, perm,
        agg_s, agg_v0, agg_v1, agg_v2);

    k_epilogue<<<N_NODES / NT1, 128, 0, stream>>>(
        agg_s, agg_v0, agg_v1, agg_v2, self_conn, species,
        w_down0, w_down1, w_sc, w_post, w_read1, w_read2,
        out, feats);
}

// Round 5
// 3716.315 us; speedup vs baseline: 1.4456x; 1.4456x over previous
//
#include <hip/hip_runtime.h>
#include <math.h>

// MACE layer, f32. Round 11: R10's launch_bounds(256,5)+prefetch re-spilled
// (VGPR 48, WRITE 10.7GB) -> reverted to R9 codegen. R9's k_edge is latency
// bound at 14 waves/CU because the 16KB hA LDS tile caps occupancy. Fix:
// split at hA. k_mlp3 (radial MLP only, writes hA E x 64 f32 = 134MB global,
// ~43us HBM round trip) + k_tp (w4 GEMM from L2 + TP scatter, hA read as
// wave-broadcast global loads, LDS only 17KB lacc window -> 8 blocks/CU,
// ~28 waves/CU latency cover). hA fits ws in <=2 big slices (R7 evidence:
// ws >= ~220MB), so no R7-style slicing tax. Register structure of both
// kernels identical to R9's proven no-spill form; launch_bounds(256,2).
// K1: node pre   Ksort: hist/scan/permute   K2: mlp3+tp   K3: epilogue

#define N_NODES 32768
#define N_EDGES 524288
#define FCH 128
#define NBASIS 8
#define HDIM 64
#define CE 64      // edges per block (N_EDGES = 8192 * CE exactly)
#define NWIN 8     // receiver-node LDS window in k_tp
#define NT1 8      // nodes per block in K1/K3
#define MIXW 640   // NP * FCH (w4 row stride)

__device__ __forceinline__ float silu(float x) { return x / (1.0f + __expf(-x)); }

constexpr float INV_SQRT128  = 0.08838834764831845f;
constexpr float INV_SQRT8    = 0.35355339059327373f;
constexpr float INV_64       = 0.125f;                 // 1/sqrt(64)
constexpr float INV_SQRT10   = 0.31622776601683794f;
constexpr float INV_SQRT1280 = 0.027950849718747374f;  // 1/sqrt(F*Z)
constexpr float INV_SQRT16   = 0.25f;
constexpr float EPSN         = 0.125f;
constexpr float C_P1         = 0.07216878364870323f;   // INV_SQRT3 * INV_64
constexpr float C_P4         = 0.08838834764831845f;   // INV_SQRT2 * INV_64

// ---------------------------------------------------------------- K1: node pre
__global__ __launch_bounds__(128) void k_node_pre(
    const float* __restrict__ ns, const float* __restrict__ nv,
    const float* __restrict__ w_skip, const float* __restrict__ w_up0,
    const float* __restrict__ w_up1, const int* __restrict__ species,
    float* __restrict__ hs, float* __restrict__ hv0, float* __restrict__ hv1,
    float* __restrict__ hv2, float* __restrict__ self_conn)
{
    __shared__ float ls[NT1][FCH];
    __shared__ float lv[3][NT1][FCH];
    __shared__ int lsp[NT1];
    const int g  = threadIdx.x;
    const int n0 = blockIdx.x * NT1;

    #pragma unroll
    for (int n = 0; n < NT1; ++n)
        ls[n][g] = ns[(size_t)(n0 + n) * FCH + g];
    for (int idx = g; idx < NT1 * FCH; idx += 128) {
        int n = idx >> 7, f = idx & 127;
        const float* src = nv + ((size_t)(n0 + n) * FCH + f) * 3;
        lv[0][n][f] = src[0];
        lv[1][n][f] = src[1];
        lv[2][n][f] = src[2];
    }
    if (g < NT1) lsp[g] = species[n0 + g];
    __syncthreads();

    const float* wk[NT1];
    #pragma unroll
    for (int n = 0; n < NT1; ++n)
        wk[n] = w_skip + (size_t)lsp[n] * FCH * FCH + g;

    float a_s[NT1], a0[NT1], a1[NT1], a2[NT1], a_k[NT1];
    #pragma unroll
    for (int n = 0; n < NT1; ++n) { a_s[n]=0; a0[n]=0; a1[n]=0; a2[n]=0; a_k[n]=0; }

    #pragma unroll 2
    for (int f = 0; f < FCH; ++f) {
        float u0 = w_up0[f * FCH + g];
        float u1 = w_up1[f * FCH + g];
        #pragma unroll
        for (int n = 0; n < NT1; ++n) {
            float s = ls[n][f];
            a_s[n] += s * u0;
            a0[n]  += lv[0][n][f] * u1;
            a1[n]  += lv[1][n][f] * u1;
            a2[n]  += lv[2][n][f] * u1;
            a_k[n] += s * wk[n][(size_t)f * FCH];
        }
    }
    #pragma unroll
    for (int n = 0; n < NT1; ++n) {
        size_t o = (size_t)(n0 + n) * FCH + g;
        hs[o]  = a_s[n] * INV_SQRT128;
        hv0[o] = a0[n]  * INV_SQRT128;
        hv1[o] = a1[n]  * INV_SQRT128;
        hv2[o] = a2[n]  * INV_SQRT128;
        self_conn[o] = a_k[n] * INV_SQRT1280;
    }
}

// ---------------------------------------------------------------- sort kernels
__global__ __launch_bounds__(256) void k_hist(
    const int* __restrict__ recv, int* __restrict__ counts)
{
    int e = blockIdx.x * 256 + threadIdx.x;
    atomicAdd(&counts[recv[e]], 1);
}

__global__ __launch_bounds__(1024) void k_scan(
    const int* __restrict__ counts, int* __restrict__ cursor)
{
    __shared__ int part[1024];
    const int t  = threadIdx.x;
    const int b0 = t * 32;
    int local[32];
    int s = 0;
    #pragma unroll
    for (int i = 0; i < 32; ++i) { local[i] = s; s += counts[b0 + i]; }
    part[t] = s;
    __syncthreads();
    for (int off = 1; off < 1024; off <<= 1) {
        int v   = part[t];
        int add = (t >= off) ? part[t - off] : 0;
        __syncthreads();
        part[t] = v + add;
        __syncthreads();
    }
    int base = (t == 0) ? 0 : part[t - 1];
    #pragma unroll
    for (int i = 0; i < 32; ++i) cursor[b0 + i] = base + local[i];
}

__global__ __launch_bounds__(256) void k_permute(
    const int* __restrict__ recv, int* __restrict__ cursor,
    int* __restrict__ perm)
{
    int e = blockIdx.x * 256 + threadIdx.x;
    int pos = atomicAdd(&cursor[recv[e]], 1);
    perm[pos] = e;
}

// ---------------------------------------------------------------- k_mlp3
// Block = 64 perm-ordered edges. 3-layer radial MLP, wave-private rows in
// LDS hA (R9's proven codegen), then block-wide coalesced writeout of the
// 16KB tile to global hA (slice-relative, row = blockIdx*CE + e).
__global__ __launch_bounds__(256, 2) void k_mlp3(
    const float* __restrict__ radial, const float* __restrict__ w1,
    const float* __restrict__ w2, const float* __restrict__ w3,
    const int* __restrict__ perm, int pos0, float* __restrict__ hAg)
{
    __shared__ __align__(16) float lrad[CE * NBASIS];  // 2KB
    __shared__ __align__(16) float hA[CE * HDIM];      // 16KB
    __shared__ int leid[CE];

    const int tid = threadIdx.x;
    const int p0  = pos0 + blockIdx.x * CE;

    if (tid < CE) leid[tid] = perm[p0 + tid];
    __syncthreads();
    for (int idx = tid; idx < CE * NBASIS; idx += 256)
        lrad[idx] = radial[(size_t)leid[idx >> 3] * NBASIS + (idx & 7)];
    __syncthreads();

    const int k    = tid & 63;
    const int grp  = tid >> 6;
    const int e_lo = grp * 16;

    {   // layer 1 (8->64)
        float w1c[NBASIS];
        #pragma unroll
        for (int j = 0; j < NBASIS; ++j) w1c[j] = w1[j * HDIM + k];
        #pragma unroll 4
        for (int e = 0; e < 16; ++e) {
            const float* r = &lrad[(e_lo + e) * NBASIS];
            float a = r[0]*w1c[0] + r[1]*w1c[1] + r[2]*w1c[2] + r[3]*w1c[3]
                    + r[4]*w1c[4] + r[5]*w1c[5] + r[6]*w1c[6] + r[7]*w1c[7];
            hA[(e_lo + e) * HDIM + k] = silu(a * INV_SQRT8);
        }
    }
    {   // layer 2 (64->64): j-outer, acc[16]
        float acc[16];
        #pragma unroll
        for (int e = 0; e < 16; ++e) acc[e] = 0.f;
        #pragma unroll 2
        for (int j = 0; j < HDIM; j += 4) {
            float wa = w2[(j+0) * HDIM + k];
            float wb = w2[(j+1) * HDIM + k];
            float wc = w2[(j+2) * HDIM + k];
            float wd = w2[(j+3) * HDIM + k];
            #pragma unroll
            for (int e = 0; e < 16; ++e) {
                float4 h = *(float4*)&hA[(e_lo + e) * HDIM + j];
                acc[e] += h.x*wa + h.y*wb + h.z*wc + h.w*wd;
            }
        }
        #pragma unroll
        for (int e = 0; e < 16; ++e)
            hA[(e_lo + e) * HDIM + k] = silu(acc[e] * INV_64);
    }
    {   // layer 3 (64->64)
        float acc[16];
        #pragma unroll
        for (int e = 0; e < 16; ++e) acc[e] = 0.f;
        #pragma unroll 2
        for (int j = 0; j < HDIM; j += 4) {
            float wa = w3[(j+0) * HDIM + k];
            float wb = w3[(j+1) * HDIM + k];
            float wc = w3[(j+2) * HDIM + k];
            float wd = w3[(j+3) * HDIM + k];
            #pragma unroll
            for (int e = 0; e < 16; ++e) {
                float4 h = *(float4*)&hA[(e_lo + e) * HDIM + j];
                acc[e] += h.x*wa + h.y*wb + h.z*wc + h.w*wd;
            }
        }
        #pragma unroll
        for (int e = 0; e < 16; ++e)
            hA[(e_lo + e) * HDIM + k] = silu(acc[e] * INV_64);
    }
    __syncthreads();

    float* dst = hAg + (size_t)blockIdx.x * CE * HDIM;
    for (int idx = tid; idx < CE * HDIM / 4; idx += 256)
        *(float4*)&dst[idx * 4] = *(float4*)&hA[idx * 4];
}

// ---------------------------------------------------------------- k_tp
// Block = 64 receiver-sorted edges. Reads hA rows from global (wave-broadcast,
// L2-hot 16KB/block), w4 from L2. Operand-grouped GEMM+TP exactly as R9
// (proven no-spill). 8-node LDS window + atomic flush into zeroed agg.
// LDS ~17KB -> 8 blocks/CU.
__global__ __launch_bounds__(256, 2) void k_tp(
    const float* __restrict__ vectors, const float* __restrict__ hAg,
    const float* __restrict__ w4,
    const float* __restrict__ hs, const float* __restrict__ hv0,
    const float* __restrict__ hv1, const float* __restrict__ hv2,
    const int* __restrict__ senders, const int* __restrict__ receivers,
    const int* __restrict__ perm, int pos0,
    float* __restrict__ agg_s, float* __restrict__ agg_v0,
    float* __restrict__ agg_v1, float* __restrict__ agg_v2)
{
    __shared__ float lY[CE][3];
    __shared__ int lsend[CE], lrecv[CE];
    __shared__ __align__(16) float laccS[NWIN * FCH];   // 4KB each
    __shared__ __align__(16) float laccV0[NWIN * FCH];
    __shared__ __align__(16) float laccV1[NWIN * FCH];
    __shared__ __align__(16) float laccV2[NWIN * FCH];

    const int tid = threadIdx.x;
    const int p0  = pos0 + blockIdx.x * CE;

    if (tid < CE) {
        int eid = perm[p0 + tid];
        lsend[tid] = senders[eid];
        lrecv[tid] = receivers[eid];
        float vx = vectors[(size_t)eid * 3 + 0];
        float vy = vectors[(size_t)eid * 3 + 1];
        float vz = vectors[(size_t)eid * 3 + 2];
        float rn = 1.0f / (sqrtf(vx*vx + vy*vy + vz*vz) + 1e-9f);
        lY[tid][0] = vx * rn; lY[tid][1] = vy * rn; lY[tid][2] = vz * rn;
    }
    for (int i = tid; i < NWIN * FCH; i += 256) {
        laccS[i] = 0.f; laccV0[i] = 0.f; laccV1[i] = 0.f; laccV2[i] = 0.f;
    }
    __syncthreads();

    const int fq = (tid & 31) * 4;
    const int eg = tid >> 5;
    const int eb = eg * 8;
    const int r0 = lrecv[0];
    const float* w4q = w4 + fq;
    const float* hrow = hAg + (size_t)blockIdx.x * CE * HDIM;

    // ===== es-group: paths 0,2 over 8 edges =====
    {
        float ma[8][4], mc[8][4];
        #pragma unroll
        for (int q = 0; q < 8; ++q)
            #pragma unroll
            for (int c = 0; c < 4; ++c) { ma[q][c] = 0.f; mc[q][c] = 0.f; }
        #pragma unroll 2
        for (int j = 0; j < HDIM; j += 2) {
            float4 w0a = *(const float4*)(w4q + (size_t)(j+0) * MIXW);
            float4 w0b = *(const float4*)(w4q + (size_t)(j+1) * MIXW);
            float4 w2a = *(const float4*)(w4q + (size_t)(j+0) * MIXW + 2*FCH);
            float4 w2b = *(const float4*)(w4q + (size_t)(j+1) * MIXW + 2*FCH);
            #pragma unroll
            for (int q = 0; q < 8; ++q) {
                float2 h = *(const float2*)&hrow[(eb + q) * HDIM + j];
                ma[q][0] += h.x*w0a.x + h.y*w0b.x;
                ma[q][1] += h.x*w0a.y + h.y*w0b.y;
                ma[q][2] += h.x*w0a.z + h.y*w0b.z;
                ma[q][3] += h.x*w0a.w + h.y*w0b.w;
                mc[q][0] += h.x*w2a.x + h.y*w2b.x;
                mc[q][1] += h.x*w2a.y + h.y*w2b.y;
                mc[q][2] += h.x*w2a.z + h.y*w2b.z;
                mc[q][3] += h.x*w2a.w + h.y*w2b.w;
            }
        }
        #pragma unroll
        for (int q = 0; q < 8; ++q) {
            const int e  = eb + q;
            const int nl = lrecv[e] - r0;
            float4 t4 = *(const float4*)(hs + (size_t)lsend[e] * FCH + fq);
            float es[4] = { t4.x, t4.y, t4.z, t4.w };
            const float Yx = lY[e][0], Yy = lY[e][1], Yz = lY[e][2];
            if (nl < NWIN) {
                const int b = nl * FCH + fq;
                #pragma unroll
                for (int c = 0; c < 4; ++c) {
                    float s = ma[q][c] * es[c] * INV_64;
                    float t = mc[q][c] * es[c] * INV_64;
                    atomicAdd(&laccS[b + c],  s);
                    atomicAdd(&laccV0[b + c], t * Yx);
                    atomicAdd(&laccV1[b + c], t * Yy);
                    atomicAdd(&laccV2[b + c], t * Yz);
                }
            } else {
                const size_t go = (size_t)lrecv[e] * FCH + fq;
                #pragma unroll
                for (int c = 0; c < 4; ++c) {
                    float s = ma[q][c] * es[c] * INV_64;
                    float t = mc[q][c] * es[c] * INV_64;
                    atomicAdd(&agg_s[go + c],  s);
                    atomicAdd(&agg_v0[go + c], t * Yx);
                    atomicAdd(&agg_v1[go + c], t * Yy);
                    atomicAdd(&agg_v2[go + c], t * Yz);
                }
            }
        }
    }

    // ===== ev-group: paths 1,3,4 in two 4-edge halves =====
    #pragma unroll
    for (int half = 0; half < 2; ++half) {
        const int e0 = eb + half * 4;
        float m1[4][4], m3[4][4], m5[4][4];
        #pragma unroll
        for (int q = 0; q < 4; ++q)
            #pragma unroll
            for (int c = 0; c < 4; ++c) { m1[q][c]=0.f; m3[q][c]=0.f; m5[q][c]=0.f; }
        #pragma unroll 4
        for (int j = 0; j < HDIM; ++j) {
            float4 wa1 = *(const float4*)(w4q + (size_t)j * MIXW + 1*FCH);
            float4 wa3 = *(const float4*)(w4q + (size_t)j * MIXW + 3*FCH);
            float4 wa4 = *(const float4*)(w4q + (size_t)j * MIXW + 4*FCH);
            #pragma unroll
            for (int q = 0; q < 4; ++q) {
                float h = hrow[(e0 + q) * HDIM + j];
                m1[q][0] += h*wa1.x; m1[q][1] += h*wa1.y;
                m1[q][2] += h*wa1.z; m1[q][3] += h*wa1.w;
                m3[q][0] += h*wa3.x; m3[q][1] += h*wa3.y;
                m3[q][2] += h*wa3.z; m3[q][3] += h*wa3.w;
                m5[q][0] += h*wa4.x; m5[q][1] += h*wa4.y;
                m5[q][2] += h*wa4.z; m5[q][3] += h*wa4.w;
            }
        }
        #pragma unroll
        for (int q = 0; q < 4; ++q) {
            const int e  = e0 + q;
            const int nl = lrecv[e] - r0;
            const size_t so = (size_t)lsend[e] * FCH + fq;
            float4 t0 = *(const float4*)(hv0 + so);
            float4 t1 = *(const float4*)(hv1 + so);
            float4 t2 = *(const float4*)(hv2 + so);
            float ev0[4] = { t0.x, t0.y, t0.z, t0.w };
            float ev1[4] = { t1.x, t1.y, t1.z, t1.w };
            float ev2[4] = { t2.x, t2.y, t2.z, t2.w };
            const float Yx = lY[e][0], Yy = lY[e][1], Yz = lY[e][2];
            if (nl < NWIN) {
                const int b = nl * FCH + fq;
                #pragma unroll
                for (int c = 0; c < 4; ++c) {
                    float d   = ev0[c]*Yx + ev1[c]*Yy + ev2[c]*Yz;
                    float sv  = m1[q][c] * d * C_P1;
                    float m3v = m3[q][c] * INV_64;
                    float m4v = m5[q][c] * C_P4;
                    float v0 = m3v*ev0[c] + m4v*(ev1[c]*Yz - ev2[c]*Yy);
                    float v1 = m3v*ev1[c] + m4v*(ev2[c]*Yx - ev0[c]*Yz);
                    float v2 = m3v*ev2[c] + m4v*(ev0[c]*Yy - ev1[c]*Yx);
                    atomicAdd(&laccS[b + c],  sv);
                    atomicAdd(&laccV0[b + c], v0);
                    atomicAdd(&laccV1[b + c], v1);
                    atomicAdd(&laccV2[b + c], v2);
                }
            } else {
                const size_t go = (size_t)lrecv[e] * FCH + fq;
                #pragma unroll
                for (int c = 0; c < 4; ++c) {
                    float d   = ev0[c]*Yx + ev1[c]*Yy + ev2[c]*Yz;
                    float sv  = m1[q][c] * d * C_P1;
                    float m3v = m3[q][c] * INV_64;
                    float m4v = m5[q][c] * C_P4;
                    float v0 = m3v*ev0[c] + m4v*(ev1[c]*Yz - ev2[c]*Yy);
                    float v1 = m3v*ev1[c] + m4v*(ev2[c]*Yx - ev0[c]*Yz);
                    float v2 = m3v*ev2[c] + m4v*(ev0[c]*Yy - ev1[c]*Yx);
                    atomicAdd(&agg_s[go + c],  sv);
                    atomicAdd(&agg_v0[go + c], v0);
                    atomicAdd(&agg_v1[go + c], v1);
                    atomicAdd(&agg_v2[go + c], v2);
                }
            }
        }
    }

    __syncthreads();   // window complete
    int span = lrecv[CE - 1] - r0;
    if (span > NWIN - 1) span = NWIN - 1;
    const int tot = (span + 1) * FCH;
    for (int i = tid; i < tot; i += 256) {
        const size_t go = (size_t)(r0 + (i >> 7)) * FCH + (i & 127);
        atomicAdd(&agg_s[go],  laccS[i]);
        atomicAdd(&agg_v0[go], laccV0[i]);
        atomicAdd(&agg_v1[go], laccV1[i]);
        atomicAdd(&agg_v2[go], laccV2[i]);
    }
}

// ---------------------------------------------------------------- K3: epilogue
__global__ __launch_bounds__(128) void k_epilogue(
    const float* __restrict__ agg_s, const float* __restrict__ agg_v0,
    const float* __restrict__ agg_v1, const float* __restrict__ agg_v2,
    const float* __restrict__ self_conn, const int* __restrict__ species,
    const float* __restrict__ w_down0, const float* __restrict__ w_down1,
    const float* __restrict__ w_sc, const float* __restrict__ w_post,
    const float* __restrict__ w_read1, const float* __restrict__ w_read2,
    float* __restrict__ out0, float* __restrict__ feats_out)
{
    __shared__ float lS[NT1][FCH];
    __shared__ float lV[3][NT1][FCH];
    __shared__ float fA[NT1][FCH];
    __shared__ float fB[NT1][FCH];
    __shared__ int lsp[NT1];
    const int g  = threadIdx.x;
    const int n0 = blockIdx.x * NT1;

    #pragma unroll
    for (int n = 0; n < NT1; ++n) {
        size_t o = (size_t)(n0 + n) * FCH + g;
        lS[n][g]    = agg_s[o]  * EPSN;
        lV[0][n][g] = agg_v0[o] * EPSN;
        lV[1][n][g] = agg_v1[o] * EPSN;
        lV[2][n][g] = agg_v2[o] * EPSN;
    }
    if (g < NT1) lsp[g] = species[n0 + g];
    __syncthreads();

    float xs[NT1], xv0[NT1], xv1[NT1], xv2[NT1];
    #pragma unroll
    for (int n = 0; n < NT1; ++n) { xs[n]=0; xv0[n]=0; xv1[n]=0; xv2[n]=0; }
    #pragma unroll 2
    for (int f = 0; f < FCH; ++f) {
        float d0 = w_down0[f * FCH + g];
        float d1 = w_down1[f * FCH + g];
        #pragma unroll
        for (int n = 0; n < NT1; ++n) {
            xs[n]  += lS[n][f] * d0;
            xv0[n] += lV[0][n][f] * d1;
            xv1[n] += lV[1][n][f] * d1;
            xv2[n] += lV[2][n][f] * d1;
        }
    }
    #pragma unroll
    for (int n = 0; n < NT1; ++n) {
        float s  = xs[n]  * INV_SQRT128;
        float v0 = xv0[n] * INV_SQRT128;
        float v1 = xv1[n] * INV_SQRT128;
        float v2 = xv2[n] * INV_SQRT128;
        int z = lsp[n];
        float wz0 = w_sc[((size_t)z * 3 + 0) * FCH + g] * INV_SQRT10;
        float wz1 = w_sc[((size_t)z * 3 + 1) * FCH + g] * INV_SQRT10;
        float wz2 = w_sc[((size_t)z * 3 + 2) * FCH + g] * INV_SQRT10;
        fA[n][g] = wz0 * s + wz1 * s * s + wz2 * (v0*v0 + v1*v1 + v2*v2);
    }
    __syncthreads();

    float fc[NT1];
    #pragma unroll
    for (int n = 0; n < NT1; ++n) fc[n] = 0;
    #pragma unroll 2
    for (int f = 0; f < FCH; ++f) {
        float wp = w_post[f * FCH + g];
        #pragma unroll
        for (int n = 0; n < NT1; ++n) fc[n] += fA[n][f] * wp;
    }
    #pragma unroll
    for (int n = 0; n < NT1; ++n) {
        size_t o = (size_t)(n0 + n) * FCH + g;
        float v = fc[n] * INV_SQRT128 + self_conn[o];
        fB[n][g] = v;
        feats_out[o] = v;
    }
    __syncthreads();

    const int n2 = g >> 4, r = g & 15;
    float acc = 0.f;
    for (int f = 0; f < FCH; ++f) acc += fB[n2][f] * w_read1[f * 16 + r];
    float t = silu(acc * INV_SQRT128);
    float val = t * w_read2[r];
    val += __shfl_down(val, 8, 16);
    val += __shfl_down(val, 4, 16);
    val += __shfl_down(val, 2, 16);
    val += __shfl_down(val, 1, 16);
    if (r == 0) out0[n0 + n2] = val * INV_SQRT16;
}

// ---------------------------------------------------------------- launch
extern "C" void kernel_launch(void* const* d_in, const int* in_sizes, int n_in,
                              void* d_out, int out_size, void* d_ws, size_t ws_size,
                              hipStream_t stream) {
    (void)in_sizes; (void)n_in; (void)out_size;
    const float* vectors      = (const float*)d_in[0];
    const float* node_scalars = (const float*)d_in[1];
    const float* node_vectors = (const float*)d_in[2];
    const float* radial       = (const float*)d_in[3];
    const float* w_skip       = (const float*)d_in[4];
    const float* w_up0        = (const float*)d_in[5];
    const float* w_up1        = (const float*)d_in[6];
    const float* mlp_w1       = (const float*)d_in[7];
    const float* mlp_w2       = (const float*)d_in[8];
    const float* mlp_w3       = (const float*)d_in[9];
    const float* mlp_w4       = (const float*)d_in[10];
    const float* w_down0      = (const float*)d_in[11];
    const float* w_down1      = (const float*)d_in[12];
    const float* w_sc         = (const float*)d_in[13];
    const float* w_post       = (const float*)d_in[14];
    const float* w_read1      = (const float*)d_in[15];
    const float* w_read2      = (const float*)d_in[16];
    const int*   senders      = (const int*)d_in[17];
    const int*   receivers    = (const int*)d_in[18];
    const int*   species      = (const int*)d_in[19];

    const size_t NF = (size_t)N_NODES * FCH;
    float* ws     = (float*)d_ws;
    float* hs     = ws;
    float* hv0    = ws + 1 * NF;
    float* hv1    = ws + 2 * NF;
    float* hv2    = ws + 3 * NF;
    float* agg_s  = ws + 4 * NF;
    float* agg_v0 = ws + 5 * NF;
    float* agg_v1 = ws + 6 * NF;
    float* agg_v2 = ws + 7 * NF;
    int* counts   = (int*)(ws + 8 * NF);      // [N]
    int* cursor   = counts + N_NODES;         // [N]
    int* perm     = cursor + N_NODES;         // [E]

    float* out       = (float*)d_out;
    float* feats     = out + N_NODES;   // final feats output
    float* self_conn = feats;           // scratch until epilogue overwrites

    hipMemsetAsync(counts, 0, N_NODES * sizeof(int), stream);
    hipMemsetAsync(agg_s, 0, 4 * NF * sizeof(float), stream);

    k_node_pre<<<N_NODES / NT1, 128, 0, stream>>>(
        node_scalars, node_vectors, w_skip, w_up0, w_up1, species,
        hs, hv0, hv1, hv2, self_conn);

    k_hist<<<N_EDGES / 256, 256, 0, stream>>>(receivers, counts);
    k_scan<<<1, 1024, 0, stream>>>(counts, cursor);
    k_permute<<<N_EDGES / 256, 256, 0, stream>>>(receivers, cursor, perm);

    // hA slice sizing: 256B/edge. ws evidence (R7): >= ~220MB -> <= 2 slices.
    const size_t fixed_b = 8 * NF * sizeof(float)
                         + (2 * (size_t)N_NODES + N_EDGES) * sizeof(int);
    const size_t haoff   = (fixed_b + 255) & ~(size_t)255;
    long long avail = (long long)ws_size - (long long)haoff;
    long long cap   = (avail > 0) ? avail / (long long)(HDIM * sizeof(float)) : 0;
    int PS = (cap >= (long long)N_EDGES) ? N_EDGES : (int)(cap & ~63LL);
    if (PS < 8192) PS = 8192;   // defensive floor (should never trigger)
    float* hAg = (float*)((char*)d_ws + haoff);

    for (int s0 = 0; s0 < N_EDGES; s0 += PS) {
        int s1 = (s0 + PS < N_EDGES) ? (s0 + PS) : N_EDGES;
        int nb = (s1 - s0) / CE;
        k_mlp3<<<nb, 256, 0, stream>>>(
            radial, mlp_w1, mlp_w2, mlp_w3, perm, s0, hAg);
        k_tp<<<nb, 256, 0, stream>>>(
            vectors, hAg, mlp_w4, hs, hv0, hv1, hv2,
            senders, receivers, perm, s0,
            agg_s, agg_v0, agg_v1, agg_v2);
    }

    k_epilogue<<<N_NODES / NT1, 128, 0, stream>>>(
        agg_s, agg_v0, agg_v1, agg_v2, self_conn, species,
        w_down0, w_down1, w_sc, w_post, w_read1, w_read2,
        out, feats);
}

// Round 6
// 2002.519 us; speedup vs baseline: 2.6828x; 1.8558x over previous
//
#include <hip/hip_runtime.h>
#include <math.h>

// MACE layer, f32. Round 12: R11 split raised occupancy but k_tp fell to 15%
// VALU: ev-group hrow became 512 scalar GLOBAL loads/thread (was LDS in R9),
// 256 LDS atomics/thread serialize on an 8-bank aliasing pattern, and the
// 134MB hAg round-trip + 2 extra dispatches cost ~500us. Fix: re-fuse on the
// R9 base (proven no-spill, VGPR 68): hA stays in LDS; NWIN 8->6 (LDS 31.5KB
// -> 5 blocks/CU); segmented register accumulation -- edges are receiver-
// sorted so a thread's 8-edge run spans ~1.5 receivers; accumulate TP in 16
// named regs, flush on receiver change only (LDS atomics ~256 -> ~70).
// K1: node pre   Ksort: hist/scan/permute   K2: fused edge   K3: epilogue

#define N_NODES 32768
#define N_EDGES 524288
#define FCH 128
#define NBASIS 8
#define HDIM 64
#define CE 64      // edges per block in K2 (N_EDGES = 8192 * CE exactly)
#define NWIN 6     // receiver-node LDS window
#define NT1 8      // nodes per block in K1/K3
#define MIXW 640   // NP * FCH (w4 row stride)

__device__ __forceinline__ float silu(float x) { return x / (1.0f + __expf(-x)); }

constexpr float INV_SQRT128  = 0.08838834764831845f;
constexpr float INV_SQRT8    = 0.35355339059327373f;
constexpr float INV_64       = 0.125f;                 // 1/sqrt(64)
constexpr float INV_SQRT10   = 0.31622776601683794f;
constexpr float INV_SQRT1280 = 0.027950849718747374f;  // 1/sqrt(F*Z)
constexpr float INV_SQRT16   = 0.25f;
constexpr float EPSN         = 0.125f;
constexpr float C_P1         = 0.07216878364870323f;   // INV_SQRT3 * INV_64
constexpr float C_P4         = 0.08838834764831845f;   // INV_SQRT2 * INV_64

// ---------------------------------------------------------------- K1: node pre
__global__ __launch_bounds__(128) void k_node_pre(
    const float* __restrict__ ns, const float* __restrict__ nv,
    const float* __restrict__ w_skip, const float* __restrict__ w_up0,
    const float* __restrict__ w_up1, const int* __restrict__ species,
    float* __restrict__ hs, float* __restrict__ hv0, float* __restrict__ hv1,
    float* __restrict__ hv2, float* __restrict__ self_conn)
{
    __shared__ float ls[NT1][FCH];
    __shared__ float lv[3][NT1][FCH];
    __shared__ int lsp[NT1];
    const int g  = threadIdx.x;
    const int n0 = blockIdx.x * NT1;

    #pragma unroll
    for (int n = 0; n < NT1; ++n)
        ls[n][g] = ns[(size_t)(n0 + n) * FCH + g];
    for (int idx = g; idx < NT1 * FCH; idx += 128) {
        int n = idx >> 7, f = idx & 127;
        const float* src = nv + ((size_t)(n0 + n) * FCH + f) * 3;
        lv[0][n][f] = src[0];
        lv[1][n][f] = src[1];
        lv[2][n][f] = src[2];
    }
    if (g < NT1) lsp[g] = species[n0 + g];
    __syncthreads();

    const float* wk[NT1];
    #pragma unroll
    for (int n = 0; n < NT1; ++n)
        wk[n] = w_skip + (size_t)lsp[n] * FCH * FCH + g;

    float a_s[NT1], a0[NT1], a1[NT1], a2[NT1], a_k[NT1];
    #pragma unroll
    for (int n = 0; n < NT1; ++n) { a_s[n]=0; a0[n]=0; a1[n]=0; a2[n]=0; a_k[n]=0; }

    #pragma unroll 2
    for (int f = 0; f < FCH; ++f) {
        float u0 = w_up0[f * FCH + g];
        float u1 = w_up1[f * FCH + g];
        #pragma unroll
        for (int n = 0; n < NT1; ++n) {
            float s = ls[n][f];
            a_s[n] += s * u0;
            a0[n]  += lv[0][n][f] * u1;
            a1[n]  += lv[1][n][f] * u1;
            a2[n]  += lv[2][n][f] * u1;
            a_k[n] += s * wk[n][(size_t)f * FCH];
        }
    }
    #pragma unroll
    for (int n = 0; n < NT1; ++n) {
        size_t o = (size_t)(n0 + n) * FCH + g;
        hs[o]  = a_s[n] * INV_SQRT128;
        hv0[o] = a0[n]  * INV_SQRT128;
        hv1[o] = a1[n]  * INV_SQRT128;
        hv2[o] = a2[n]  * INV_SQRT128;
        self_conn[o] = a_k[n] * INV_SQRT1280;
    }
}

// ---------------------------------------------------------------- sort kernels
__global__ __launch_bounds__(256) void k_hist(
    const int* __restrict__ recv, int* __restrict__ counts)
{
    int e = blockIdx.x * 256 + threadIdx.x;
    atomicAdd(&counts[recv[e]], 1);
}

__global__ __launch_bounds__(1024) void k_scan(
    const int* __restrict__ counts, int* __restrict__ cursor)
{
    __shared__ int part[1024];
    const int t  = threadIdx.x;
    const int b0 = t * 32;
    int local[32];
    int s = 0;
    #pragma unroll
    for (int i = 0; i < 32; ++i) { local[i] = s; s += counts[b0 + i]; }
    part[t] = s;
    __syncthreads();
    for (int off = 1; off < 1024; off <<= 1) {
        int v   = part[t];
        int add = (t >= off) ? part[t - off] : 0;
        __syncthreads();
        part[t] = v + add;
        __syncthreads();
    }
    int base = (t == 0) ? 0 : part[t - 1];
    #pragma unroll
    for (int i = 0; i < 32; ++i) cursor[b0 + i] = base + local[i];
}

__global__ __launch_bounds__(256) void k_permute(
    const int* __restrict__ recv, int* __restrict__ cursor,
    int* __restrict__ perm)
{
    int e = blockIdx.x * 256 + threadIdx.x;
    int pos = atomicAdd(&cursor[recv[e]], 1);
    perm[pos] = e;
}

// flush macros (all indices compile-time; named scalar accumulators)
#define FLUSH_ES()                                                        \
    do {                                                                  \
        if (cur < NWIN) {                                                 \
            const int b_ = cur * FCH + fq;                                \
            atomicAdd(&laccS[b_+0], aS0); atomicAdd(&laccS[b_+1], aS1);   \
            atomicAdd(&laccS[b_+2], aS2); atomicAdd(&laccS[b_+3], aS3);   \
            atomicAdd(&laccV0[b_+0], aV00); atomicAdd(&laccV0[b_+1], aV01);\
            atomicAdd(&laccV0[b_+2], aV02); atomicAdd(&laccV0[b_+3], aV03);\
            atomicAdd(&laccV1[b_+0], aV10); atomicAdd(&laccV1[b_+1], aV11);\
            atomicAdd(&laccV1[b_+2], aV12); atomicAdd(&laccV1[b_+3], aV13);\
            atomicAdd(&laccV2[b_+0], aV20); atomicAdd(&laccV2[b_+1], aV21);\
            atomicAdd(&laccV2[b_+2], aV22); atomicAdd(&laccV2[b_+3], aV23);\
        } else {                                                          \
            const size_t g_ = (size_t)(r0 + cur) * FCH + fq;              \
            atomicAdd(&agg_s[g_+0], aS0); atomicAdd(&agg_s[g_+1], aS1);   \
            atomicAdd(&agg_s[g_+2], aS2); atomicAdd(&agg_s[g_+3], aS3);   \
            atomicAdd(&agg_v0[g_+0], aV00); atomicAdd(&agg_v0[g_+1], aV01);\
            atomicAdd(&agg_v0[g_+2], aV02); atomicAdd(&agg_v0[g_+3], aV03);\
            atomicAdd(&agg_v1[g_+0], aV10); atomicAdd(&agg_v1[g_+1], aV11);\
            atomicAdd(&agg_v1[g_+2], aV12); atomicAdd(&agg_v1[g_+3], aV13);\
            atomicAdd(&agg_v2[g_+0], aV20); atomicAdd(&agg_v2[g_+1], aV21);\
            atomicAdd(&agg_v2[g_+2], aV22); atomicAdd(&agg_v2[g_+3], aV23);\
        }                                                                 \
    } while (0)

#define ZERO_ACC()                                                        \
    do { aS0=0;aS1=0;aS2=0;aS3=0; aV00=0;aV01=0;aV02=0;aV03=0;            \
         aV10=0;aV11=0;aV12=0;aV13=0; aV20=0;aV21=0;aV22=0;aV23=0; } while (0)

// ---------------------------------------------------------------- K2: fused
// Block = 64 receiver-sorted edges. MLP wave-private in-place in LDS hA
// (R9's proven codegen). Operand-grouped path GEMMs (es: p0,p2 over 8 edges;
// ev: p1,p3,p4 over two 4-edge halves). TP accumulates in registers with
// receiver-segment flushes into the 6-node LDS window / global overflow.
__global__ __launch_bounds__(256, 2) void k_edge(
    const float* __restrict__ vectors, const float* __restrict__ radial,
    const float* __restrict__ w1, const float* __restrict__ w2,
    const float* __restrict__ w3, const float* __restrict__ w4,
    const float* __restrict__ hs, const float* __restrict__ hv0,
    const float* __restrict__ hv1, const float* __restrict__ hv2,
    const int* __restrict__ senders, const int* __restrict__ receivers,
    const int* __restrict__ perm,
    float* __restrict__ agg_s, float* __restrict__ agg_v0,
    float* __restrict__ agg_v1, float* __restrict__ agg_v2)
{
    __shared__ __align__(16) float lrad[CE * NBASIS];  // 2KB
    __shared__ __align__(16) float hA[CE * HDIM];      // 16KB
    __shared__ float lY[CE][3];
    __shared__ int leid[CE], lsend[CE], lrecv[CE];
    __shared__ __align__(16) float laccS[NWIN * FCH];  // 3KB each
    __shared__ __align__(16) float laccV0[NWIN * FCH];
    __shared__ __align__(16) float laccV1[NWIN * FCH];
    __shared__ __align__(16) float laccV2[NWIN * FCH];

    const int tid = threadIdx.x;
    const int p0  = blockIdx.x * CE;

    if (tid < CE) {
        int eid = perm[p0 + tid];
        leid[tid]  = eid;
        lsend[tid] = senders[eid];
        lrecv[tid] = receivers[eid];
        float vx = vectors[(size_t)eid * 3 + 0];
        float vy = vectors[(size_t)eid * 3 + 1];
        float vz = vectors[(size_t)eid * 3 + 2];
        float rn = 1.0f / (sqrtf(vx*vx + vy*vy + vz*vz) + 1e-9f);
        lY[tid][0] = vx * rn; lY[tid][1] = vy * rn; lY[tid][2] = vz * rn;
    }
    for (int i = tid; i < NWIN * FCH; i += 256) {
        laccS[i] = 0.f; laccV0[i] = 0.f; laccV1[i] = 0.f; laccV2[i] = 0.f;
    }
    __syncthreads();
    for (int idx = tid; idx < CE * NBASIS; idx += 256)
        lrad[idx] = radial[(size_t)leid[idx >> 3] * NBASIS + (idx & 7)];
    __syncthreads();   // barrier #2 (last before flush)

    // ---- radial MLP, wave-private rows [grp*16, +16), in-place in hA ----
    const int k    = tid & 63;
    const int grp  = tid >> 6;
    const int e_lo = grp * 16;

    {   // layer 1 (8->64)
        float w1c[NBASIS];
        #pragma unroll
        for (int j = 0; j < NBASIS; ++j) w1c[j] = w1[j * HDIM + k];
        #pragma unroll 4
        for (int e = 0; e < 16; ++e) {
            const float* r = &lrad[(e_lo + e) * NBASIS];
            float a = r[0]*w1c[0] + r[1]*w1c[1] + r[2]*w1c[2] + r[3]*w1c[3]
                    + r[4]*w1c[4] + r[5]*w1c[5] + r[6]*w1c[6] + r[7]*w1c[7];
            hA[(e_lo + e) * HDIM + k] = silu(a * INV_SQRT8);
        }
    }
    {   // layer 2 (64->64): j-outer, acc[16]
        float acc[16];
        #pragma unroll
        for (int e = 0; e < 16; ++e) acc[e] = 0.f;
        #pragma unroll 2
        for (int j = 0; j < HDIM; j += 4) {
            float wa = w2[(j+0) * HDIM + k];
            float wb = w2[(j+1) * HDIM + k];
            float wc = w2[(j+2) * HDIM + k];
            float wd = w2[(j+3) * HDIM + k];
            #pragma unroll
            for (int e = 0; e < 16; ++e) {
                float4 h = *(float4*)&hA[(e_lo + e) * HDIM + j];
                acc[e] += h.x*wa + h.y*wb + h.z*wc + h.w*wd;
            }
        }
        #pragma unroll
        for (int e = 0; e < 16; ++e)
            hA[(e_lo + e) * HDIM + k] = silu(acc[e] * INV_64);
    }
    {   // layer 3 (64->64)
        float acc[16];
        #pragma unroll
        for (int e = 0; e < 16; ++e) acc[e] = 0.f;
        #pragma unroll 2
        for (int j = 0; j < HDIM; j += 4) {
            float wa = w3[(j+0) * HDIM + k];
            float wb = w3[(j+1) * HDIM + k];
            float wc = w3[(j+2) * HDIM + k];
            float wd = w3[(j+3) * HDIM + k];
            #pragma unroll
            for (int e = 0; e < 16; ++e) {
                float4 h = *(float4*)&hA[(e_lo + e) * HDIM + j];
                acc[e] += h.x*wa + h.y*wb + h.z*wc + h.w*wd;
            }
        }
        #pragma unroll
        for (int e = 0; e < 16; ++e)
            hA[(e_lo + e) * HDIM + k] = silu(acc[e] * INV_64);
    }

    // ---- operand-grouped path GEMMs + segmented TP ----
    const int fq = (tid & 31) * 4;
    const int eg = tid >> 5;
    const int eb = eg * 8;
    const int r0 = lrecv[0];
    const float* w4q = w4 + fq;

    // ===== es-group: paths 0 and 2 over 8 edges =====
    {
        float ma[8][4], mc[8][4];
        #pragma unroll
        for (int q = 0; q < 8; ++q)
            #pragma unroll
            for (int c = 0; c < 4; ++c) { ma[q][c] = 0.f; mc[q][c] = 0.f; }
        #pragma unroll 2
        for (int j = 0; j < HDIM; j += 2) {
            float4 w0a = *(const float4*)(w4q + (size_t)(j+0) * MIXW);
            float4 w0b = *(const float4*)(w4q + (size_t)(j+1) * MIXW);
            float4 w2a = *(const float4*)(w4q + (size_t)(j+0) * MIXW + 2*FCH);
            float4 w2b = *(const float4*)(w4q + (size_t)(j+1) * MIXW + 2*FCH);
            #pragma unroll
            for (int q = 0; q < 8; ++q) {
                float2 h = *(float2*)&hA[(eb + q) * HDIM + j];
                ma[q][0] += h.x*w0a.x + h.y*w0b.x;
                ma[q][1] += h.x*w0a.y + h.y*w0b.y;
                ma[q][2] += h.x*w0a.z + h.y*w0b.z;
                ma[q][3] += h.x*w0a.w + h.y*w0b.w;
                mc[q][0] += h.x*w2a.x + h.y*w2b.x;
                mc[q][1] += h.x*w2a.y + h.y*w2b.y;
                mc[q][2] += h.x*w2a.z + h.y*w2b.z;
                mc[q][3] += h.x*w2a.w + h.y*w2b.w;
            }
        }

        float aS0,aS1,aS2,aS3, aV00,aV01,aV02,aV03;
        float aV10,aV11,aV12,aV13, aV20,aV21,aV22,aV23;
        ZERO_ACC();
        int cur = lrecv[eb] - r0;
        #pragma unroll
        for (int q = 0; q < 8; ++q) {
            const int e  = eb + q;
            const int nl = lrecv[e] - r0;
            if (nl != cur) { FLUSH_ES(); ZERO_ACC(); cur = nl; }
            float4 t4 = *(const float4*)(hs + (size_t)lsend[e] * FCH + fq);
            const float Yx = lY[e][0], Yy = lY[e][1], Yz = lY[e][2];
            aS0 += ma[q][0] * t4.x * INV_64;
            aS1 += ma[q][1] * t4.y * INV_64;
            aS2 += ma[q][2] * t4.z * INV_64;
            aS3 += ma[q][3] * t4.w * INV_64;
            float t0 = mc[q][0] * t4.x * INV_64;
            float t1 = mc[q][1] * t4.y * INV_64;
            float t2 = mc[q][2] * t4.z * INV_64;
            float t3 = mc[q][3] * t4.w * INV_64;
            aV00 += t0*Yx; aV01 += t1*Yx; aV02 += t2*Yx; aV03 += t3*Yx;
            aV10 += t0*Yy; aV11 += t1*Yy; aV12 += t2*Yy; aV13 += t3*Yy;
            aV20 += t0*Yz; aV21 += t1*Yz; aV22 += t2*Yz; aV23 += t3*Yz;
        }
        FLUSH_ES();
    }

    // ===== ev-group: paths 1,3,4 in two 4-edge halves =====
    #pragma unroll
    for (int half = 0; half < 2; ++half) {
        const int e0 = eb + half * 4;
        float m1[4][4], m3[4][4], m5[4][4];
        #pragma unroll
        for (int q = 0; q < 4; ++q)
            #pragma unroll
            for (int c = 0; c < 4; ++c) { m1[q][c]=0.f; m3[q][c]=0.f; m5[q][c]=0.f; }
        #pragma unroll 4
        for (int j = 0; j < HDIM; ++j) {
            float4 wa1 = *(const float4*)(w4q + (size_t)j * MIXW + 1*FCH);
            float4 wa3 = *(const float4*)(w4q + (size_t)j * MIXW + 3*FCH);
            float4 wa4 = *(const float4*)(w4q + (size_t)j * MIXW + 4*FCH);
            #pragma unroll
            for (int q = 0; q < 4; ++q) {
                float h = hA[(e0 + q) * HDIM + j];
                m1[q][0] += h*wa1.x; m1[q][1] += h*wa1.y;
                m1[q][2] += h*wa1.z; m1[q][3] += h*wa1.w;
                m3[q][0] += h*wa3.x; m3[q][1] += h*wa3.y;
                m3[q][2] += h*wa3.z; m3[q][3] += h*wa3.w;
                m5[q][0] += h*wa4.x; m5[q][1] += h*wa4.y;
                m5[q][2] += h*wa4.z; m5[q][3] += h*wa4.w;
            }
        }

        float aS0,aS1,aS2,aS3, aV00,aV01,aV02,aV03;
        float aV10,aV11,aV12,aV13, aV20,aV21,aV22,aV23;
        ZERO_ACC();
        int cur = lrecv[e0] - r0;
        #pragma unroll
        for (int q = 0; q < 4; ++q) {
            const int e  = e0 + q;
            const int nl = lrecv[e] - r0;
            if (nl != cur) { FLUSH_ES(); ZERO_ACC(); cur = nl; }
            const size_t so = (size_t)lsend[e] * FCH + fq;
            float4 t0 = *(const float4*)(hv0 + so);
            float4 t1 = *(const float4*)(hv1 + so);
            float4 t2 = *(const float4*)(hv2 + so);
            const float Yx = lY[e][0], Yy = lY[e][1], Yz = lY[e][2];
            // c = 0..3 unrolled with named lanes of t0/t1/t2
            {   // c=0
                float d   = t0.x*Yx + t1.x*Yy + t2.x*Yz;
                float m3v = m3[q][0] * INV_64;
                float m4v = m5[q][0] * C_P4;
                aS0  += m1[q][0] * d * C_P1;
                aV00 += m3v*t0.x + m4v*(t1.x*Yz - t2.x*Yy);
                aV10 += m3v*t1.x + m4v*(t2.x*Yx - t0.x*Yz);
                aV20 += m3v*t2.x + m4v*(t0.x*Yy - t1.x*Yx);
            }
            {   // c=1
                float d   = t0.y*Yx + t1.y*Yy + t2.y*Yz;
                float m3v = m3[q][1] * INV_64;
                float m4v = m5[q][1] * C_P4;
                aS1  += m1[q][1] * d * C_P1;
                aV01 += m3v*t0.y + m4v*(t1.y*Yz - t2.y*Yy);
                aV11 += m3v*t1.y + m4v*(t2.y*Yx - t0.y*Yz);
                aV21 += m3v*t2.y + m4v*(t0.y*Yy - t1.y*Yx);
            }
            {   // c=2
                float d   = t0.z*Yx + t1.z*Yy + t2.z*Yz;
                float m3v = m3[q][2] * INV_64;
                float m4v = m5[q][2] * C_P4;
                aS2  += m1[q][2] * d * C_P1;
                aV02 += m3v*t0.z + m4v*(t1.z*Yz - t2.z*Yy);
                aV12 += m3v*t1.z + m4v*(t2.z*Yx - t0.z*Yz);
                aV22 += m3v*t2.z + m4v*(t0.z*Yy - t1.z*Yx);
            }
            {   // c=3
                float d   = t0.w*Yx + t1.w*Yy + t2.w*Yz;
                float m3v = m3[q][3] * INV_64;
                float m4v = m5[q][3] * C_P4;
                aS3  += m1[q][3] * d * C_P1;
                aV03 += m3v*t0.w + m4v*(t1.w*Yz - t2.w*Yy);
                aV13 += m3v*t1.w + m4v*(t2.w*Yx - t0.w*Yz);
                aV23 += m3v*t2.w + m4v*(t0.w*Yy - t1.w*Yx);
            }
        }
        FLUSH_ES();
    }

    __syncthreads();   // barrier #3: window complete
    int span = lrecv[CE - 1] - r0;
    if (span > NWIN - 1) span = NWIN - 1;
    const int tot = (span + 1) * FCH;
    for (int i = tid; i < tot; i += 256) {
        const size_t go = (size_t)(r0 + (i >> 7)) * FCH + (i & 127);
        atomicAdd(&agg_s[go],  laccS[i]);
        atomicAdd(&agg_v0[go], laccV0[i]);
        atomicAdd(&agg_v1[go], laccV1[i]);
        atomicAdd(&agg_v2[go], laccV2[i]);
    }
}

// ---------------------------------------------------------------- K3: epilogue
__global__ __launch_bounds__(128) void k_epilogue(
    const float* __restrict__ agg_s, const float* __restrict__ agg_v0,
    const float* __restrict__ agg_v1, const float* __restrict__ agg_v2,
    const float* __restrict__ self_conn, const int* __restrict__ species,
    const float* __restrict__ w_down0, const float* __restrict__ w_down1,
    const float* __restrict__ w_sc, const float* __restrict__ w_post,
    const float* __restrict__ w_read1, const float* __restrict__ w_read2,
    float* __restrict__ out0, float* __restrict__ feats_out)
{
    __shared__ float lS[NT1][FCH];
    __shared__ float lV[3][NT1][FCH];
    __shared__ float fA[NT1][FCH];
    __shared__ float fB[NT1][FCH];
    __shared__ int lsp[NT1];
    const int g  = threadIdx.x;
    const int n0 = blockIdx.x * NT1;

    #pragma unroll
    for (int n = 0; n < NT1; ++n) {
        size_t o = (size_t)(n0 + n) * FCH + g;
        lS[n][g]    = agg_s[o]  * EPSN;
        lV[0][n][g] = agg_v0[o] * EPSN;
        lV[1][n][g] = agg_v1[o] * EPSN;
        lV[2][n][g] = agg_v2[o] * EPSN;
    }
    if (g < NT1) lsp[g] = species[n0 + g];
    __syncthreads();

    float xs[NT1], xv0[NT1], xv1[NT1], xv2[NT1];
    #pragma unroll
    for (int n = 0; n < NT1; ++n) { xs[n]=0; xv0[n]=0; xv1[n]=0; xv2[n]=0; }
    #pragma unroll 2
    for (int f = 0; f < FCH; ++f) {
        float d0 = w_down0[f * FCH + g];
        float d1 = w_down1[f * FCH + g];
        #pragma unroll
        for (int n = 0; n < NT1; ++n) {
            xs[n]  += lS[n][f] * d0;
            xv0[n] += lV[0][n][f] * d1;
            xv1[n] += lV[1][n][f] * d1;
            xv2[n] += lV[2][n][f] * d1;
        }
    }
    #pragma unroll
    for (int n = 0; n < NT1; ++n) {
        float s  = xs[n]  * INV_SQRT128;
        float v0 = xv0[n] * INV_SQRT128;
        float v1 = xv1[n] * INV_SQRT128;
        float v2 = xv2[n] * INV_SQRT128;
        int z = lsp[n];
        float wz0 = w_sc[((size_t)z * 3 + 0) * FCH + g] * INV_SQRT10;
        float wz1 = w_sc[((size_t)z * 3 + 1) * FCH + g] * INV_SQRT10;
        float wz2 = w_sc[((size_t)z * 3 + 2) * FCH + g] * INV_SQRT10;
        fA[n][g] = wz0 * s + wz1 * s * s + wz2 * (v0*v0 + v1*v1 + v2*v2);
    }
    __syncthreads();

    float fc[NT1];
    #pragma unroll
    for (int n = 0; n < NT1; ++n) fc[n] = 0;
    #pragma unroll 2
    for (int f = 0; f < FCH; ++f) {
        float wp = w_post[f * FCH + g];
        #pragma unroll
        for (int n = 0; n < NT1; ++n) fc[n] += fA[n][f] * wp;
    }
    #pragma unroll
    for (int n = 0; n < NT1; ++n) {
        size_t o = (size_t)(n0 + n) * FCH + g;
        float v = fc[n] * INV_SQRT128 + self_conn[o];
        fB[n][g] = v;
        feats_out[o] = v;
    }
    __syncthreads();

    const int n2 = g >> 4, r = g & 15;
    float acc = 0.f;
    for (int f = 0; f < FCH; ++f) acc += fB[n2][f] * w_read1[f * 16 + r];
    float t = silu(acc * INV_SQRT128);
    float val = t * w_read2[r];
    val += __shfl_down(val, 8, 16);
    val += __shfl_down(val, 4, 16);
    val += __shfl_down(val, 2, 16);
    val += __shfl_down(val, 1, 16);
    if (r == 0) out0[n0 + n2] = val * INV_SQRT16;
}

// ---------------------------------------------------------------- launch
extern "C" void kernel_launch(void* const* d_in, const int* in_sizes, int n_in,
                              void* d_out, int out_size, void* d_ws, size_t ws_size,
                              hipStream_t stream) {
    (void)in_sizes; (void)n_in; (void)out_size; (void)ws_size;
    const float* vectors      = (const float*)d_in[0];
    const float* node_scalars = (const float*)d_in[1];
    const float* node_vectors = (const float*)d_in[2];
    const float* radial       = (const float*)d_in[3];
    const float* w_skip       = (const float*)d_in[4];
    const float* w_up0        = (const float*)d_in[5];
    const float* w_up1        = (const float*)d_in[6];
    const float* mlp_w1       = (const float*)d_in[7];
    const float* mlp_w2       = (const float*)d_in[8];
    const float* mlp_w3       = (const float*)d_in[9];
    const float* mlp_w4       = (const float*)d_in[10];
    const float* w_down0      = (const float*)d_in[11];
    const float* w_down1      = (const float*)d_in[12];
    const float* w_sc         = (const float*)d_in[13];
    const float* w_post       = (const float*)d_in[14];
    const float* w_read1      = (const float*)d_in[15];
    const float* w_read2      = (const float*)d_in[16];
    const int*   senders      = (const int*)d_in[17];
    const int*   receivers    = (const int*)d_in[18];
    const int*   species      = (const int*)d_in[19];

    const size_t NF = (size_t)N_NODES * FCH;
    float* ws     = (float*)d_ws;
    float* hs     = ws;
    float* hv0    = ws + 1 * NF;
    float* hv1    = ws + 2 * NF;
    float* hv2    = ws + 3 * NF;
    float* agg_s  = ws + 4 * NF;
    float* agg_v0 = ws + 5 * NF;
    float* agg_v1 = ws + 6 * NF;
    float* agg_v2 = ws + 7 * NF;
    int* counts   = (int*)(ws + 8 * NF);      // [N]
    int* cursor   = counts + N_NODES;         // [N]
    int* perm     = cursor + N_NODES;         // [E]

    float* out       = (float*)d_out;
    float* feats     = out + N_NODES;   // final feats output
    float* self_conn = feats;           // scratch until epilogue overwrites

    hipMemsetAsync(counts, 0, N_NODES * sizeof(int), stream);
    hipMemsetAsync(agg_s, 0, 4 * NF * sizeof(float), stream);

    k_node_pre<<<N_NODES / NT1, 128, 0, stream>>>(
        node_scalars, node_vectors, w_skip, w_up0, w_up1, species,
        hs, hv0, hv1, hv2, self_conn);

    k_hist<<<N_EDGES / 256, 256, 0, stream>>>(receivers, counts);
    k_scan<<<1, 1024, 0, stream>>>(counts, cursor);
    k_permute<<<N_EDGES / 256, 256, 0, stream>>>(receivers, cursor, perm);

    k_edge<<<N_EDGES / CE, 256, 0, stream>>>(
        vectors, radial, mlp_w1, mlp_w2, mlp_w3, mlp_w4,
        hs, hv0, hv1, hv2, senders, receivers, perm,
        agg_s, agg_v0, agg_v1, agg_v2);

    k_epilogue<<<N_NODES / NT1, 128, 0, stream>>>(
        agg_s, agg_v0, agg_v1, agg_v2, self_conn, species,
        w_down0, w_down1, w_sc, w_post, w_read1, w_read2,
        out, feats);
}